// Round 16
// baseline (896.600 us; speedup 1.0000x reference)
//
#include <hip/hip_runtime.h>
#include <hip/hip_fp16.h>
#include <math.h>

#define T_STEPS 8
#define F_IN    8
#define HID     32
#define KCH     5
#define PERIODS 8
#define NB      64

typedef __attribute__((ext_vector_type(8))) _Float16 half8_t;
typedef __attribute__((ext_vector_type(4))) float    f32x4_t;

__device__ __forceinline__ float sigmoidf_(float x) { return 1.f / (1.f + __expf(-x)); }
__device__ __forceinline__ float tanhf_(float x) {
    float e = __expf(2.f * x);
    return 1.f - 2.f / (e + 1.f);
}

// ---------------- graph setup ----------------

__global__ void k_count(const int* __restrict__ src, const int* __restrict__ dst,
                        int* __restrict__ degi, int* __restrict__ cnt, int E) {
    int e = blockIdx.x * blockDim.x + threadIdx.x;
    if (e >= E) return;
    int s = src[e], d = dst[e];
    if (s != d) {
        atomicAdd(&degi[s], 1);
        atomicAdd(&cnt[d], 1);
    }
}

__global__ void k_hist2(const int* __restrict__ cnt, int* __restrict__ hist,
                        int N, int NT) {
    __shared__ int h[256];
    int tid = threadIdx.x, blk = blockIdx.x;
    h[tid] = 0;
    __syncthreads();
    int n = blk * 256 + tid;
    if (n < N) atomicAdd(&h[min(cnt[n], 255)], 1);
    __syncthreads();
    hist[tid * NT + blk] = h[tid];
}

// exclusive scan, single block 1024 threads, 32 elems/thread; valid n <= 32768
__global__ void __launch_bounds__(1024) k_scan(const int* __restrict__ in,
                                               int* __restrict__ outp, int n) {
    __shared__ int wsum[16];
    int tid = threadIdx.x;
    int base = tid * 32;
    int v[32];
    int s = 0;
    #pragma unroll
    for (int i = 0; i < 32; ++i) {
        int idx = base + i;
        int t = (idx < n) ? in[idx] : 0;
        v[i] = t; s += t;
    }
    int lane = tid & 63, wave = tid >> 6;
    int incl = s;
    #pragma unroll
    for (int off = 1; off < 64; off <<= 1) {
        int t = __shfl_up(incl, off, 64);
        if (lane >= off) incl += t;
    }
    if (lane == 63) wsum[wave] = incl;
    __syncthreads();
    if (tid < 64) {
        int w = (tid < 16) ? wsum[tid] : 0;
        int iw = w;
        #pragma unroll
        for (int off = 1; off < 16; off <<= 1) {
            int t = __shfl_up(iw, off, 64);
            if (tid >= off) iw += t;
        }
        if (tid < 16) wsum[tid] = iw - w;
    }
    __syncthreads();
    int excl = wsum[wave] + (incl - s);
    #pragma unroll
    for (int i = 0; i < 32; ++i) {
        int idx = base + i;
        if (idx < n) outp[idx] = excl;
        excl += v[i];
    }
    if (tid == 1023) outp[n] = wsum[15] + incl;
}

__global__ void k_permscat2(const int* __restrict__ cnt, const int* __restrict__ degi,
                            const int* __restrict__ histbase,
                            int* __restrict__ perm, int* __restrict__ iperm,
                            int* __restrict__ cntp, float* __restrict__ dis,
                            int N, int NT) {
    __shared__ int key[256];
    int tid = threadIdx.x, blk = blockIdx.x;
    int n = blk * 256 + tid;
    int k = (n < N) ? min(cnt[n], 255) : -1;
    key[tid] = k;
    __syncthreads();
    if (n < N) {
        int r = 0;
        for (int j = 0; j < tid; ++j) r += (key[j] == k);
        int pos = histbase[k * NT + blk] + r;
        perm[pos] = n;
        iperm[n] = pos;
        cntp[pos] = cnt[n];
        int dg = degi[n];
        dis[n] = (dg > 0) ? rsqrtf((float)dg) : 0.f;
    }
}

// merged: edge scatter (4B packed cv: low16 = permuted col, high16 = fp16 -norm)
// + x transpose/permute/fp16 + MFMA B-fragment packing
__global__ void k_scatxt(const int* __restrict__ src, const int* __restrict__ dst,
                         const float* __restrict__ dis, const int* __restrict__ rowptr,
                         const int* __restrict__ iperm, int* __restrict__ fill,
                         unsigned int* __restrict__ cv, const float* __restrict__ xall,
                         __half* __restrict__ xb,
                         const float* __restrict__ Wh, __half* __restrict__ Bpack,
                         const float* __restrict__ Wx, __half* __restrict__ Bxpack,
                         int N, int E) {
    int gsz = (int)(gridDim.x * blockDim.x);
    int gtid = blockIdx.x * blockDim.x + threadIdx.x;
    for (int e = gtid; e < E; e += gsz) {
        int s = src[e], d = dst[e];
        if (s != d) {
            float nv = -dis[s] * dis[d];
            unsigned short h16 = __half_as_ushort(__float2half(nv));
            int dp = iperm[d];
            int p = atomicAdd(&fill[dp], 1);
            cv[rowptr[dp] + p] = (unsigned int)(unsigned short)iperm[s]
                               | ((unsigned int)h16 << 16);
        }
    }
    for (int i = gtid; i < N * T_STEPS; i += gsz) {
        int n = i >> 3, t = i & 7;
        float4 a = *(const float4*)(xall + ((size_t)t * N + n) * 8);
        float4 b = *(const float4*)(xall + ((size_t)t * N + n) * 8 + 4);
        __half2 h[4];
        h[0] = __float22half2_rn(make_float2(a.x, a.y));
        h[1] = __float22half2_rn(make_float2(a.z, a.w));
        h[2] = __float22half2_rn(make_float2(b.x, b.y));
        h[3] = __float22half2_rn(make_float2(b.z, b.w));
        *(float4*)(xb + (size_t)iperm[n] * 64 + t * 8) = *(float4*)h;
    }
    for (int i = gtid; i < KCH * 8 * 64 * 8; i += gsz) {
        int j = i & 7, lane = (i >> 3) & 63, nt = (i >> 9) & 7, k = i >> 12;
        int col = lane & 15, quad = lane >> 4;
        int kk = quad * 8 + j;
        int o = nt * 16 + col, g = o >> 5, h = o & 31;
        Bpack[i] = __float2half(Wh[(((g * KCH + k) * 32) + kk) * 32 + h]);
    }
    for (int i = gtid; i < 2 * 8 * 64 * 8; i += gsz) {
        int j = i & 7, lane = (i >> 3) & 63, nt = (i >> 9) & 7, c = i >> 12;
        int col = lane & 15, quad = lane >> 4;
        int kk = c * 32 + quad * 8 + j;
        int kcheb = kk >> 3, ch = kk & 7;
        int o = nt * 16 + col, g = o >> 5, h = o & 31;
        float v = (kcheb < KCH) ? Wx[(((g * KCH + kcheb) * 8) + ch) * 32 + h] : 0.f;
        Bxpack[i] = __float2half(v);
    }
}

// ---- A^2 setup: per-node relative offsets + deg2 (thread per node) ----
__global__ void k_off2(const int* __restrict__ rowptr, const unsigned int* __restrict__ cv,
                       int* __restrict__ eoffrel, int* __restrict__ rowidx,
                       int* __restrict__ deg2, int N) {
    int i = blockIdx.x * blockDim.x + threadIdx.x;
    if (i >= N) return;
    int beg = rowptr[i], end = rowptr[i + 1];
    int off = 0;
    for (int e = beg; e < end; ++e) {
        int j = (int)(cv[e] & 0xffffu);
        eoffrel[e] = off;
        rowidx[e] = i;
        off += rowptr[j + 1] - rowptr[j];
    }
    deg2[i] = off;
}

// ---- A^2 build: thread per A-edge slot copies src-row's cv slice scaled ----
// cv stores -n; product of two stored values = +n_ij*n_jk = L_hat^2 weight.
__global__ void k_copy2(const int* __restrict__ rowptr, const unsigned int* __restrict__ cv,
                        const int* __restrict__ eoffrel, const int* __restrict__ rowidx,
                        const int* __restrict__ rowptr2, unsigned int* __restrict__ cv2,
                        int N, int E) {
    int e = blockIdx.x * blockDim.x + threadIdx.x;
    if (e >= rowptr[N]) return;
    unsigned int pv = cv[e];
    int j = (int)(pv & 0xffffu);
    float wij = __half2float(__ushort_as_half((unsigned short)(pv >> 16)));
    int i = rowidx[e];
    unsigned int* dstp = cv2 + rowptr2[i] + eoffrel[e];
    int jb = rowptr[j], je = rowptr[j + 1];
    for (int kp = jb; kp < je; ++kp) {
        unsigned int kv = cv[kp];
        float wjk = __half2float(__ushort_as_half((unsigned short)(kv >> 16)));
        unsigned short pw = __half_as_ushort(__float2half(wij * wjk));
        dstp[kp - jb] = (kv & 0xffffu) | ((unsigned int)pw << 16);
    }
}

// ---------------- Laplacian: pull CSR, fp16 features, ES-way edge split -----
template <int C, int ES>
__global__ void __launch_bounds__(256) k_lap_h(__half* __restrict__ outp,
                                               const __half* __restrict__ xin,
                                               const __half* __restrict__ xprev,
                                               float alpha, float beta,
                                               const int* __restrict__ rowptr,
                                               const unsigned int* __restrict__ cv,
                                               int N) {
    constexpr int Q = C / 8;
    constexpr int W = Q * ES;
    int idx = blockIdx.x * 256 + threadIdx.x;
    int node = idx / W;
    int r = idx % W;
    int q = r % Q, s = r / Q;
    if (node >= N) return;
    int beg = rowptr[node], end = rowptr[node + 1];
    float a0 = 0.f, a1 = 0.f, a2 = 0.f, a3 = 0.f, a4 = 0.f, a5 = 0.f, a6 = 0.f, a7 = 0.f;
    #pragma unroll 8
    for (int j = beg + s; j < end; j += ES) {
        unsigned int pv = cv[j];
        int pcol = (int)(pv & 0xffffu);
        float nv = __half2float(__ushort_as_half((unsigned short)(pv >> 16)));
        float4 raw = *(const float4*)(xin + (size_t)pcol * C + q * 8);
        const __half2* h = (const __half2*)&raw;
        float2 f0 = __half22float2(h[0]);
        float2 f1 = __half22float2(h[1]);
        float2 f2 = __half22float2(h[2]);
        float2 f3 = __half22float2(h[3]);
        a0 += nv * f0.x; a1 += nv * f0.y; a2 += nv * f1.x; a3 += nv * f1.y;
        a4 += nv * f2.x; a5 += nv * f2.y; a6 += nv * f3.x; a7 += nv * f3.y;
    }
    #pragma unroll
    for (int m = Q; m < W; m <<= 1) {
        a0 += __shfl_xor(a0, m, 64); a1 += __shfl_xor(a1, m, 64);
        a2 += __shfl_xor(a2, m, 64); a3 += __shfl_xor(a3, m, 64);
        a4 += __shfl_xor(a4, m, 64); a5 += __shfl_xor(a5, m, 64);
        a6 += __shfl_xor(a6, m, 64); a7 += __shfl_xor(a7, m, 64);
    }
    if (s != 0) return;
    size_t off = (size_t)node * C + q * 8;
    float r0 = alpha * a0, r1 = alpha * a1, r2 = alpha * a2, r3 = alpha * a3;
    float r4 = alpha * a4, r5 = alpha * a5, r6 = alpha * a6, r7 = alpha * a7;
    if (beta != 0.f) {
        float4 raw = *(const float4*)(xprev + off);
        const __half2* h = (const __half2*)&raw;
        float2 f0 = __half22float2(h[0]);
        float2 f1 = __half22float2(h[1]);
        float2 f2 = __half22float2(h[2]);
        float2 f3 = __half22float2(h[3]);
        r0 += beta * f0.x; r1 += beta * f0.y; r2 += beta * f1.x; r3 += beta * f1.y;
        r4 += beta * f2.x; r5 += beta * f2.y; r6 += beta * f3.x; r7 += beta * f3.y;
    }
    __half2 o[4];
    o[0] = __float22half2_rn(make_float2(r0, r1));
    o[1] = __float22half2_rn(make_float2(r2, r3));
    o[2] = __float22half2_rn(make_float2(r4, r5));
    o[3] = __float22half2_rn(make_float2(r6, r7));
    *(float4*)(outp + off) = *(float4*)o;
}

// ---------------- fused T1+T2 stage: T1 = L(H), T2 = 2 L^2(H) - H -----------
// Blocks [0, B1) compute T1 via 1-hop cv (16 lanes/node); blocks [B1, B1+B2)
// compute T2 via the precomputed 2-hop cv2 (64 lanes/node, ~16 trips). Both
// gather from the same L2-resident H rows -> concurrent, one dispatch.
__global__ void __launch_bounds__(256) k_lapAB(
    __half* __restrict__ T1, __half* __restrict__ T2, const __half* __restrict__ H,
    const int* __restrict__ rowptr, const unsigned int* __restrict__ cv,
    const int* __restrict__ rowptr2, const unsigned int* __restrict__ cv2,
    int B1, int N) {
    int bid = blockIdx.x;
    int tid = threadIdx.x;
    if (bid < B1) {
        // T1 = L(H): C=32, 16 lanes/node (Q=4, ES=4)
        int idx = bid * 256 + tid;
        int node = idx >> 4;
        int r = idx & 15;
        int q = r & 3, s = r >> 2;
        if (node >= N) return;
        int beg = rowptr[node], end = rowptr[node + 1];
        float a0 = 0.f, a1 = 0.f, a2 = 0.f, a3 = 0.f, a4 = 0.f, a5 = 0.f, a6 = 0.f, a7 = 0.f;
        #pragma unroll 8
        for (int j = beg + s; j < end; j += 4) {
            unsigned int pv = cv[j];
            int pcol = (int)(pv & 0xffffu);
            float nv = __half2float(__ushort_as_half((unsigned short)(pv >> 16)));
            float4 raw = *(const float4*)(H + (size_t)pcol * HID + q * 8);
            const __half2* h = (const __half2*)&raw;
            float2 f0 = __half22float2(h[0]);
            float2 f1 = __half22float2(h[1]);
            float2 f2 = __half22float2(h[2]);
            float2 f3 = __half22float2(h[3]);
            a0 += nv * f0.x; a1 += nv * f0.y; a2 += nv * f1.x; a3 += nv * f1.y;
            a4 += nv * f2.x; a5 += nv * f2.y; a6 += nv * f3.x; a7 += nv * f3.y;
        }
        #pragma unroll
        for (int m = 4; m < 16; m <<= 1) {
            a0 += __shfl_xor(a0, m, 64); a1 += __shfl_xor(a1, m, 64);
            a2 += __shfl_xor(a2, m, 64); a3 += __shfl_xor(a3, m, 64);
            a4 += __shfl_xor(a4, m, 64); a5 += __shfl_xor(a5, m, 64);
            a6 += __shfl_xor(a6, m, 64); a7 += __shfl_xor(a7, m, 64);
        }
        if (s != 0) return;
        __half2 o[4];
        o[0] = __float22half2_rn(make_float2(a0, a1));
        o[1] = __float22half2_rn(make_float2(a2, a3));
        o[2] = __float22half2_rn(make_float2(a4, a5));
        o[3] = __float22half2_rn(make_float2(a6, a7));
        *(float4*)(T1 + (size_t)node * HID + q * 8) = *(float4*)o;
    } else {
        // T2 = 2 L^2(H) - H: C=32, 64 lanes/node over cv2 (Q=4, 16 parities)
        int idx = (bid - B1) * 256 + tid;
        int node = idx >> 6;
        int r = idx & 63;
        int q = r & 3, s = r >> 2;
        if (node >= N) return;
        int beg = rowptr2[node], end = rowptr2[node + 1];
        float a0 = 0.f, a1 = 0.f, a2 = 0.f, a3 = 0.f, a4 = 0.f, a5 = 0.f, a6 = 0.f, a7 = 0.f;
        #pragma unroll 8
        for (int j = beg + s; j < end; j += 16) {
            unsigned int pv = cv2[j];
            int pcol = (int)(pv & 0xffffu);
            float nv = __half2float(__ushort_as_half((unsigned short)(pv >> 16)));
            float4 raw = *(const float4*)(H + (size_t)pcol * HID + q * 8);
            const __half2* h = (const __half2*)&raw;
            float2 f0 = __half22float2(h[0]);
            float2 f1 = __half22float2(h[1]);
            float2 f2 = __half22float2(h[2]);
            float2 f3 = __half22float2(h[3]);
            a0 += nv * f0.x; a1 += nv * f0.y; a2 += nv * f1.x; a3 += nv * f1.y;
            a4 += nv * f2.x; a5 += nv * f2.y; a6 += nv * f3.x; a7 += nv * f3.y;
        }
        #pragma unroll
        for (int m = 4; m < 64; m <<= 1) {
            a0 += __shfl_xor(a0, m, 64); a1 += __shfl_xor(a1, m, 64);
            a2 += __shfl_xor(a2, m, 64); a3 += __shfl_xor(a3, m, 64);
            a4 += __shfl_xor(a4, m, 64); a5 += __shfl_xor(a5, m, 64);
            a6 += __shfl_xor(a6, m, 64); a7 += __shfl_xor(a7, m, 64);
        }
        if (s != 0) return;
        size_t off = (size_t)node * HID + q * 8;
        float4 raw = *(const float4*)(H + off);
        const __half2* h = (const __half2*)&raw;
        float2 f0 = __half22float2(h[0]);
        float2 f1 = __half22float2(h[1]);
        float2 f2 = __half22float2(h[2]);
        float2 f3 = __half22float2(h[3]);
        __half2 o[4];
        o[0] = __float22half2_rn(make_float2(2.f * a0 - f0.x, 2.f * a1 - f0.y));
        o[1] = __float22half2_rn(make_float2(2.f * a2 - f1.x, 2.f * a3 - f1.y));
        o[2] = __float22half2_rn(make_float2(2.f * a4 - f2.x, 2.f * a5 - f2.y));
        o[3] = __float22half2_rn(make_float2(2.f * a6 - f3.x, 2.f * a7 - f3.y));
        *(float4*)(T2 + off) = *(float4*)o;
    }
}

// ---------------- fused lap#4 + MFMA gate GEMM + LSTM (+ out head) ----------
__global__ void __launch_bounds__(256) k_lapstep(
    const __half* __restrict__ xb, const __half* __restrict__ TXB,
    __half* __restrict__ THall, float* __restrict__ Cst,
    const __half* __restrict__ Bpack, const __half* __restrict__ Bxpack,
    const float* __restrict__ w_c, const float* __restrict__ bg,
    const float* __restrict__ W_lin, const float* __restrict__ b_lin,
    const int* __restrict__ perm, float* __restrict__ out,
    const int* __restrict__ rowptr, const unsigned int* __restrict__ cv,
    int t, int doOut, int N) {
    __shared__ __half T4s[16 * 32];
    __shared__ float Gs[16 * 128];
    __shared__ float Hs[16 * 33];
    int tid = threadIdx.x;
    int base = blockIdx.x * 16;
    int lane = tid & 63, wv = tid >> 6;
    int col = lane & 15, quad = lane >> 4;

    // phase 1: T4 = 2*L(T3) - T2 for block's 16 nodes (16 lanes/node)
    {
        const __half* T3 = THall + (size_t)3 * N * HID;
        const __half* T2 = THall + (size_t)2 * N * HID;
        int nl = tid >> 4;
        int r = tid & 15;
        int q = r & 3, s = r >> 2;
        int node = base + nl; if (node >= N) node = N - 1;
        int beg = rowptr[node], end = rowptr[node + 1];
        float a0 = 0.f, a1 = 0.f, a2 = 0.f, a3 = 0.f, a4 = 0.f, a5 = 0.f, a6 = 0.f, a7 = 0.f;
        #pragma unroll 8
        for (int j = beg + s; j < end; j += 4) {
            unsigned int pv = cv[j];
            int pcol = (int)(pv & 0xffffu);
            float nv = __half2float(__ushort_as_half((unsigned short)(pv >> 16)));
            float4 raw = *(const float4*)(T3 + (size_t)pcol * HID + q * 8);
            const __half2* h = (const __half2*)&raw;
            float2 f0 = __half22float2(h[0]);
            float2 f1 = __half22float2(h[1]);
            float2 f2 = __half22float2(h[2]);
            float2 f3 = __half22float2(h[3]);
            a0 += nv * f0.x; a1 += nv * f0.y; a2 += nv * f1.x; a3 += nv * f1.y;
            a4 += nv * f2.x; a5 += nv * f2.y; a6 += nv * f3.x; a7 += nv * f3.y;
        }
        #pragma unroll
        for (int m = 4; m < 16; m <<= 1) {
            a0 += __shfl_xor(a0, m, 64); a1 += __shfl_xor(a1, m, 64);
            a2 += __shfl_xor(a2, m, 64); a3 += __shfl_xor(a3, m, 64);
            a4 += __shfl_xor(a4, m, 64); a5 += __shfl_xor(a5, m, 64);
            a6 += __shfl_xor(a6, m, 64); a7 += __shfl_xor(a7, m, 64);
        }
        if (s == 0) {
            float4 raw = *(const float4*)(T2 + (size_t)node * HID + q * 8);
            const __half2* h = (const __half2*)&raw;
            float2 f0 = __half22float2(h[0]);
            float2 f1 = __half22float2(h[1]);
            float2 f2 = __half22float2(h[2]);
            float2 f3 = __half22float2(h[3]);
            __half2 o[4];
            o[0] = __float22half2_rn(make_float2(2.f * a0 - f0.x, 2.f * a1 - f0.y));
            o[1] = __float22half2_rn(make_float2(2.f * a2 - f1.x, 2.f * a3 - f1.y));
            o[2] = __float22half2_rn(make_float2(2.f * a4 - f2.x, 2.f * a5 - f2.y));
            o[3] = __float22half2_rn(make_float2(2.f * a6 - f3.x, 2.f * a7 - f3.y));
            *(float4*)(T4s + nl * 32 + q * 8) = *(float4*)o;
        }
    }
    __syncthreads();

    // phase 2: gate GEMM (wave wv: nt = {wv, 4+wv})
    int node_a = base + col; if (node_a >= N) node_a = N - 1;
    f32x4_t acc[2];
    #pragma unroll
    for (int i = 0; i < 2; ++i) {
        float b = bg[(wv + 4 * i) * 16 + col];
        acc[i][0] = b; acc[i][1] = b; acc[i][2] = b; acc[i][3] = b;
    }
    const half8_t* Bx = (const half8_t*)Bxpack;
    const half8_t* Bp = (const half8_t*)Bpack;
    {
        const __half* sp0 = (quad == 0)
            ? (xb + (size_t)node_a * 64 + t * 8)
            : (TXB + ((size_t)(quad - 1) * N + node_a) * 64 + t * 8);
        half8_t ax0 = *(const half8_t*)sp0;
        half8_t ax1 = {};
        if (quad == 0)
            ax1 = *(const half8_t*)(TXB + ((size_t)3 * N + node_a) * 64 + t * 8);
        #pragma unroll
        for (int i = 0; i < 2; ++i) {
            int nt = wv + 4 * i;
            acc[i] = __builtin_amdgcn_mfma_f32_16x16x32_f16(ax0, Bx[nt * 64 + lane], acc[i], 0, 0, 0);
            acc[i] = __builtin_amdgcn_mfma_f32_16x16x32_f16(ax1, Bx[(8 + nt) * 64 + lane], acc[i], 0, 0, 0);
        }
    }
    #pragma unroll
    for (int k = 0; k < 4; ++k) {
        half8_t a = *(const half8_t*)(THall + ((size_t)k * N + node_a) * 32 + quad * 8);
        #pragma unroll
        for (int i = 0; i < 2; ++i) {
            int nt = wv + 4 * i;
            acc[i] = __builtin_amdgcn_mfma_f32_16x16x32_f16(a, Bp[(k * 8 + nt) * 64 + lane], acc[i], 0, 0, 0);
        }
    }
    {
        half8_t a = *(const half8_t*)(T4s + col * 32 + quad * 8);
        #pragma unroll
        for (int i = 0; i < 2; ++i) {
            int nt = wv + 4 * i;
            acc[i] = __builtin_amdgcn_mfma_f32_16x16x32_f16(a, Bp[(4 * 8 + nt) * 64 + lane], acc[i], 0, 0, 0);
        }
    }

    // phase 3: stage gate pre-acts
    #pragma unroll
    for (int i = 0; i < 2; ++i) {
        int nt = wv + 4 * i;
        #pragma unroll
        for (int reg = 0; reg < 4; ++reg)
            Gs[(quad * 4 + reg) * 128 + nt * 16 + col] = acc[i][reg];
    }
    __syncthreads();

    // phase 4: LSTM pointwise
    #pragma unroll
    for (int pp = 0; pp < 2; ++pp) {
        int p = tid + pp * 256;
        int nl = p >> 5, h = p & 31;
        int node = base + nl;
        if (node < N) {
            const float* g = Gs + nl * 128;
            size_t idx = (size_t)node * 32 + h;
            float Co = Cst[idx];
            float I  = sigmoidf_(g[h]      + w_c[h]      * Co);
            float F  = sigmoidf_(g[32 + h] + w_c[32 + h] * Co);
            float Tg = tanhf_(g[64 + h]);
            float Cn = F * Co + I * Tg;
            float O  = sigmoidf_(g[96 + h] + w_c[64 + h] * Cn);
            float Hn = O * tanhf_(Cn);
            Cst[idx] = Cn;
            THall[idx] = __float2half(Hn);
            if (doOut) Hs[nl * 33 + h] = fmaxf(Hn, 0.f);
        } else if (doOut) {
            Hs[nl * 33 + h] = 0.f;
        }
    }

    // phase 5: output head
    if (doOut) {
        __syncthreads();
        if (tid < 128) {
            int nl = tid >> 3, pp = tid & 7;
            int node = base + nl;
            if (node < N) {
                float a0 = b_lin[pp];
                const float* hp = Hs + nl * 33;
                #pragma unroll
                for (int h = 0; h < HID; ++h)
                    a0 += hp[h] * W_lin[pp * HID + h];
                out[(size_t)perm[node] * PERIODS + pp] = a0;
            }
        }
    }
}

// ---------------- fused lapx#4 + t=0 x-GEMM + pointwise ----------------------
// 16 nodes/block. Phase 1: TXB3 = 2*L(TXB2) - TXB1 (C=64, 16 lanes/node),
// written globally (needed by all later timesteps) AND kept in LDS for the
// t=0 GEMM. Phase 2-4: x-GEMM + LSTM pointwise with C=H=0.
__global__ void __launch_bounds__(256) k_lapstep0(
    const __half* __restrict__ xb, const __half* __restrict__ TXB,
    __half* __restrict__ TXB3, __half* __restrict__ THall, float* __restrict__ Cst,
    const __half* __restrict__ Bxpack,
    const float* __restrict__ w_c, const float* __restrict__ bg,
    const int* __restrict__ rowptr, const unsigned int* __restrict__ cv, int N) {
    __shared__ __half X3s[16 * 64];     // 2 KB
    __shared__ float Gs[16 * 128];
    int tid = threadIdx.x;
    int base = blockIdx.x * 16;
    int lane = tid & 63, wv = tid >> 6;
    int col = lane & 15, quad = lane >> 4;

    // phase 1: TXB3 rows for block's 16 nodes (C=64: Q=8, s in {0,1})
    {
        const __half* T2 = TXB + (size_t)2 * N * 64;
        const __half* T1 = TXB + (size_t)1 * N * 64;
        int nl = tid >> 4;
        int r = tid & 15;
        int q = r & 7, s = r >> 3;
        int node = base + nl; if (node >= N) node = N - 1;
        int beg = rowptr[node], end = rowptr[node + 1];
        float a0 = 0.f, a1 = 0.f, a2 = 0.f, a3 = 0.f, a4 = 0.f, a5 = 0.f, a6 = 0.f, a7 = 0.f;
        #pragma unroll 8
        for (int j = beg + s; j < end; j += 2) {
            unsigned int pv = cv[j];
            int pcol = (int)(pv & 0xffffu);
            float nv = __half2float(__ushort_as_half((unsigned short)(pv >> 16)));
            float4 raw = *(const float4*)(T2 + (size_t)pcol * 64 + q * 8);
            const __half2* h = (const __half2*)&raw;
            float2 f0 = __half22float2(h[0]);
            float2 f1 = __half22float2(h[1]);
            float2 f2 = __half22float2(h[2]);
            float2 f3 = __half22float2(h[3]);
            a0 += nv * f0.x; a1 += nv * f0.y; a2 += nv * f1.x; a3 += nv * f1.y;
            a4 += nv * f2.x; a5 += nv * f2.y; a6 += nv * f3.x; a7 += nv * f3.y;
        }
        a0 += __shfl_xor(a0, 8, 64); a1 += __shfl_xor(a1, 8, 64);
        a2 += __shfl_xor(a2, 8, 64); a3 += __shfl_xor(a3, 8, 64);
        a4 += __shfl_xor(a4, 8, 64); a5 += __shfl_xor(a5, 8, 64);
        a6 += __shfl_xor(a6, 8, 64); a7 += __shfl_xor(a7, 8, 64);
        if (s == 0) {
            size_t off = (size_t)node * 64 + q * 8;
            float4 raw = *(const float4*)(T1 + off);
            const __half2* h = (const __half2*)&raw;
            float2 f0 = __half22float2(h[0]);
            float2 f1 = __half22float2(h[1]);
            float2 f2 = __half22float2(h[2]);
            float2 f3 = __half22float2(h[3]);
            __half2 o[4];
            o[0] = __float22half2_rn(make_float2(2.f * a0 - f0.x, 2.f * a1 - f0.y));
            o[1] = __float22half2_rn(make_float2(2.f * a2 - f1.x, 2.f * a3 - f1.y));
            o[2] = __float22half2_rn(make_float2(2.f * a4 - f2.x, 2.f * a5 - f2.y));
            o[3] = __float22half2_rn(make_float2(2.f * a6 - f3.x, 2.f * a7 - f3.y));
            *(float4*)(TXB3 + off) = *(float4*)o;
            *(float4*)(X3s + nl * 64 + q * 8) = *(float4*)o;
        }
    }
    __syncthreads();

    // phase 2: x-GEMM (t = 0)
    int node_a = base + col; if (node_a >= N) node_a = N - 1;
    f32x4_t acc[2];
    #pragma unroll
    for (int i = 0; i < 2; ++i) {
        float b = bg[(wv + 4 * i) * 16 + col];
        acc[i][0] = b; acc[i][1] = b; acc[i][2] = b; acc[i][3] = b;
    }
    const half8_t* Bx = (const half8_t*)Bxpack;
    {
        const __half* sp0 = (quad == 0)
            ? (xb + (size_t)node_a * 64)
            : (TXB + ((size_t)(quad - 1) * N + node_a) * 64);
        half8_t ax0 = *(const half8_t*)sp0;
        half8_t ax1 = {};
        if (quad == 0)
            ax1 = *(const half8_t*)(X3s + col * 64);   // t = 0 slice
        #pragma unroll
        for (int i = 0; i < 2; ++i) {
            int nt = wv + 4 * i;
            acc[i] = __builtin_amdgcn_mfma_f32_16x16x32_f16(ax0, Bx[nt * 64 + lane], acc[i], 0, 0, 0);
            acc[i] = __builtin_amdgcn_mfma_f32_16x16x32_f16(ax1, Bx[(8 + nt) * 64 + lane], acc[i], 0, 0, 0);
        }
    }

    // phase 3: stage
    #pragma unroll
    for (int i = 0; i < 2; ++i) {
        int nt = wv + 4 * i;
        #pragma unroll
        for (int reg = 0; reg < 4; ++reg)
            Gs[(quad * 4 + reg) * 128 + nt * 16 + col] = acc[i][reg];
    }
    __syncthreads();

    // phase 4: LSTM pointwise with C = 0
    #pragma unroll
    for (int pp = 0; pp < 2; ++pp) {
        int p = tid + pp * 256;
        int nl = p >> 5, h = p & 31;
        int node = base + nl;
        if (node < N) {
            const float* g = Gs + nl * 128;
            size_t idx = (size_t)node * 32 + h;
            float I  = sigmoidf_(g[h]);
            float Tg = tanhf_(g[64 + h]);
            float Cn = I * Tg;
            float O  = sigmoidf_(g[96 + h] + w_c[64 + h] * Cn);
            Cst[idx] = Cn;
            THall[idx] = __float2half(O * tanhf_(Cn));
        }
    }
}

// ---------------- launch ----------------

extern "C" void kernel_launch(void* const* d_in, const int* in_sizes, int n_in,
                              void* d_out, int out_size, void* d_ws, size_t ws_size,
                              hipStream_t stream) {
    const float* xall  = (const float*)d_in[0];
    const int*   ei    = (const int*)d_in[1];
    const float* Wx    = (const float*)d_in[2];
    const float* Wh    = (const float*)d_in[3];
    const float* w_c   = (const float*)d_in[4];
    const float* bg    = (const float*)d_in[5];
    const float* W_lin = (const float*)d_in[6];
    const float* b_lin = (const float*)d_in[7];
    float* out = (float*)d_out;

    const int E = in_sizes[1] / 2;
    const int N = in_sizes[0] / (T_STEPS * F_IN);
    const int NT = (N + 255) / 256;
    const int* src = ei;
    const int* dst = ei + E;

    char* p = (char*)d_ws;
    auto carve = [&](size_t bytes) -> void* {
        void* r = (void*)p;
        p += (bytes + 255) & ~(size_t)255;
        return r;
    };
    // zero block: degi, cnt, fill, Cst
    char* zero_begin = p;
    int*    degi  = (int*)   carve((size_t)N * 4);
    int*    cnt   = (int*)   carve((size_t)N * 4);
    int*    fill  = (int*)   carve((size_t)N * 4);
    float*  Cst   = (float*) carve((size_t)N * HID * 4);
    size_t zero_bytes = (size_t)(p - zero_begin);
    __half* THall = (__half*)carve((size_t)4 * N * HID * 2);   // slices 0..3
    int*    hist     = (int*)   carve((size_t)256 * NT * 4);
    int*    histbase = (int*)   carve(((size_t)256 * NT + 1) * 4);
    float*  dis      = (float*) carve((size_t)N * 4);
    int*    perm     = (int*)   carve((size_t)N * 4);
    int*    iperm    = (int*)   carve((size_t)N * 4);
    int*    cntp     = (int*)   carve((size_t)N * 4);
    int*    rowptr   = (int*)   carve((size_t)(N + 1) * 4);
    unsigned int* cv = (unsigned int*)carve((size_t)E * 4);
    __half* xb       = (__half*)carve((size_t)N * 64 * 2);
    __half* TXB      = (__half*)carve((size_t)4 * N * 64 * 2);
    __half* Bpack    = (__half*)carve((size_t)KCH * 8 * 64 * 8 * 2);
    __half* Bxpack   = (__half*)carve((size_t)2 * 8 * 64 * 8 * 2);
    int*    eoffrel  = (int*)   carve((size_t)E * 4);
    int*    rowidx   = (int*)   carve((size_t)E * 4);
    int*    deg2     = (int*)   carve((size_t)N * 4);
    int*    rowptr2  = (int*)   carve((size_t)(N + 1) * 4);
    unsigned int* cv2 = (unsigned int*)carve((size_t)16 * 1024 * 1024 * 4);  // 64 MB (C-S bound 8.2M)

    hipMemsetAsync(zero_begin, 0, zero_bytes, stream);

    const int TB = 256;
    const int gE = (E + TB - 1) / TB;
    const int gN = (N + TB - 1) / TB;
    k_count<<<gE, TB, 0, stream>>>(src, dst, degi, cnt, E);
    k_hist2<<<NT, TB, 0, stream>>>(cnt, hist, N, NT);
    k_scan<<<1, 1024, 0, stream>>>(hist, histbase, 256 * NT);
    k_permscat2<<<NT, TB, 0, stream>>>(cnt, degi, histbase, perm, iperm, cntp, dis, N, NT);
    k_scan<<<1, 1024, 0, stream>>>(cntp, rowptr, N);
    k_scatxt<<<gE, TB, 0, stream>>>(src, dst, dis, rowptr, iperm, fill, cv, xall, xb,
                                    Wh, Bpack, Wx, Bxpack, N, E);
    // A^2 build
    k_off2<<<gN, TB, 0, stream>>>(rowptr, cv, eoffrel, rowidx, deg2, N);
    k_scan<<<1, 1024, 0, stream>>>(deg2, rowptr2, N);
    k_copy2<<<gE, TB, 0, stream>>>(rowptr, cv, eoffrel, rowidx, rowptr2, cv2, N, E);

    // x-phase Chebyshev: 3 standalone laps + fused (lapx#4 + t=0 step)
    __half* TXB0 = TXB;
    __half* TXB1 = TXB + (size_t)N * 64;
    __half* TXB2 = TXB + (size_t)2 * N * 64;
    __half* TXB3 = TXB + (size_t)3 * N * 64;
    const int lapx_grid = (N * 32 + TB - 1) / TB;
    k_lap_h<64, 4><<<lapx_grid, TB, 0, stream>>>(TXB0, xb,   nullptr, 1.f,  0.f, rowptr, cv, N);
    k_lap_h<64, 4><<<lapx_grid, TB, 0, stream>>>(TXB1, TXB0, xb,      2.f, -1.f, rowptr, cv, N);
    k_lap_h<64, 4><<<lapx_grid, TB, 0, stream>>>(TXB2, TXB1, TXB0,    2.f, -1.f, rowptr, cv, N);

    const int lapstep_grid = (N + 15) / 16;
    __half* TH0 = THall;
    __half* TH1 = THall + (size_t)N * HID;
    __half* TH2 = THall + (size_t)2 * N * HID;
    __half* TH3 = THall + (size_t)3 * N * HID;

    // t = 0: fused lapx#4 + x-GEMM + pointwise (H0 = C0 = 0)
    k_lapstep0<<<lapstep_grid, TB, 0, stream>>>(xb, TXB, TXB3, THall, Cst, Bxpack,
                                                w_c, bg, rowptr, cv, N);

    const int B1 = (N * 16 + TB - 1) / TB;   // T1 blocks
    const int B2 = (N * 64 + TB - 1) / TB;   // T2 blocks
    const int laph_grid = (N * 16 + TB - 1) / TB;

    for (int t = 1; t < T_STEPS; ++t) {
        k_lapAB<<<B1 + B2, TB, 0, stream>>>(TH1, TH2, TH0, rowptr, cv, rowptr2, cv2, B1, N);
        k_lap_h<HID, 4><<<laph_grid, TB, 0, stream>>>(TH3, TH2, TH1, 2.f, -1.f, rowptr, cv, N);
        k_lapstep<<<lapstep_grid, TB, 0, stream>>>(xb, TXB, THall, Cst, Bpack, Bxpack,
                                                   w_c, bg, W_lin, b_lin, perm, out,
                                                   rowptr, cv, t,
                                                   (t == T_STEPS - 1) ? 1 : 0, N);
    }
}

// Round 17
// 605.376 us; speedup vs baseline: 1.4811x; 1.4811x over previous
//
#include <hip/hip_runtime.h>
#include <hip/hip_fp16.h>
#include <math.h>

#define T_STEPS 8
#define F_IN    8
#define HID     32
#define KCH     5
#define PERIODS 8
#define NB      64

typedef __attribute__((ext_vector_type(8))) _Float16 half8_t;
typedef __attribute__((ext_vector_type(4))) float    f32x4_t;

__device__ __forceinline__ float sigmoidf_(float x) { return 1.f / (1.f + __expf(-x)); }
__device__ __forceinline__ float tanhf_(float x) {
    float e = __expf(2.f * x);
    return 1.f - 2.f / (e + 1.f);
}

// ---------------- graph setup ----------------

__global__ void k_count(const int* __restrict__ src, const int* __restrict__ dst,
                        int* __restrict__ degi, int* __restrict__ cnt, int E) {
    int e = blockIdx.x * blockDim.x + threadIdx.x;
    if (e >= E) return;
    int s = src[e], d = dst[e];
    if (s != d) {
        atomicAdd(&degi[s], 1);
        atomicAdd(&cnt[d], 1);
    }
}

__global__ void k_hist2(const int* __restrict__ cnt, int* __restrict__ hist,
                        int N, int NT) {
    __shared__ int h[256];
    int tid = threadIdx.x, blk = blockIdx.x;
    h[tid] = 0;
    __syncthreads();
    int n = blk * 256 + tid;
    if (n < N) atomicAdd(&h[min(cnt[n], 255)], 1);
    __syncthreads();
    hist[tid * NT + blk] = h[tid];
}

// exclusive scan, single block 1024 threads, 32 elems/thread; valid n <= 32768
__global__ void __launch_bounds__(1024) k_scan(const int* __restrict__ in,
                                               int* __restrict__ outp, int n) {
    __shared__ int wsum[16];
    int tid = threadIdx.x;
    int base = tid * 32;
    int v[32];
    int s = 0;
    #pragma unroll
    for (int i = 0; i < 32; ++i) {
        int idx = base + i;
        int t = (idx < n) ? in[idx] : 0;
        v[i] = t; s += t;
    }
    int lane = tid & 63, wave = tid >> 6;
    int incl = s;
    #pragma unroll
    for (int off = 1; off < 64; off <<= 1) {
        int t = __shfl_up(incl, off, 64);
        if (lane >= off) incl += t;
    }
    if (lane == 63) wsum[wave] = incl;
    __syncthreads();
    if (tid < 64) {
        int w = (tid < 16) ? wsum[tid] : 0;
        int iw = w;
        #pragma unroll
        for (int off = 1; off < 16; off <<= 1) {
            int t = __shfl_up(iw, off, 64);
            if (tid >= off) iw += t;
        }
        if (tid < 16) wsum[tid] = iw - w;
    }
    __syncthreads();
    int excl = wsum[wave] + (incl - s);
    #pragma unroll
    for (int i = 0; i < 32; ++i) {
        int idx = base + i;
        if (idx < n) outp[idx] = excl;
        excl += v[i];
    }
    if (tid == 1023) outp[n] = wsum[15] + incl;
}

__global__ void k_permscat2(const int* __restrict__ cnt, const int* __restrict__ degi,
                            const int* __restrict__ histbase,
                            int* __restrict__ perm, int* __restrict__ iperm,
                            int* __restrict__ cntp, float* __restrict__ dis,
                            int N, int NT) {
    __shared__ int key[256];
    int tid = threadIdx.x, blk = blockIdx.x;
    int n = blk * 256 + tid;
    int k = (n < N) ? min(cnt[n], 255) : -1;
    key[tid] = k;
    __syncthreads();
    if (n < N) {
        int r = 0;
        for (int j = 0; j < tid; ++j) r += (key[j] == k);
        int pos = histbase[k * NT + blk] + r;
        perm[pos] = n;
        iperm[n] = pos;
        cntp[pos] = cnt[n];
        int dg = degi[n];
        dis[n] = (dg > 0) ? rsqrtf((float)dg) : 0.f;
    }
}

// merged: edge scatter (4B packed cv: low16 = permuted col, high16 = fp16 -norm)
// + x transpose/permute/fp16 + MFMA B-fragment packing
__global__ void k_scatxt(const int* __restrict__ src, const int* __restrict__ dst,
                         const float* __restrict__ dis, const int* __restrict__ rowptr,
                         const int* __restrict__ iperm, int* __restrict__ fill,
                         unsigned int* __restrict__ cv, const float* __restrict__ xall,
                         __half* __restrict__ xb,
                         const float* __restrict__ Wh, __half* __restrict__ Bpack,
                         const float* __restrict__ Wx, __half* __restrict__ Bxpack,
                         int N, int E) {
    int gsz = (int)(gridDim.x * blockDim.x);
    int gtid = blockIdx.x * blockDim.x + threadIdx.x;
    for (int e = gtid; e < E; e += gsz) {
        int s = src[e], d = dst[e];
        if (s != d) {
            float nv = -dis[s] * dis[d];
            unsigned short h16 = __half_as_ushort(__float2half(nv));
            int dp = iperm[d];
            int p = atomicAdd(&fill[dp], 1);
            cv[rowptr[dp] + p] = (unsigned int)(unsigned short)iperm[s]
                               | ((unsigned int)h16 << 16);
        }
    }
    for (int i = gtid; i < N * T_STEPS; i += gsz) {
        int n = i >> 3, t = i & 7;
        float4 a = *(const float4*)(xall + ((size_t)t * N + n) * 8);
        float4 b = *(const float4*)(xall + ((size_t)t * N + n) * 8 + 4);
        __half2 h[4];
        h[0] = __float22half2_rn(make_float2(a.x, a.y));
        h[1] = __float22half2_rn(make_float2(a.z, a.w));
        h[2] = __float22half2_rn(make_float2(b.x, b.y));
        h[3] = __float22half2_rn(make_float2(b.z, b.w));
        *(float4*)(xb + (size_t)iperm[n] * 64 + t * 8) = *(float4*)h;
    }
    for (int i = gtid; i < KCH * 8 * 64 * 8; i += gsz) {
        int j = i & 7, lane = (i >> 3) & 63, nt = (i >> 9) & 7, k = i >> 12;
        int col = lane & 15, quad = lane >> 4;
        int kk = quad * 8 + j;
        int o = nt * 16 + col, g = o >> 5, h = o & 31;
        Bpack[i] = __float2half(Wh[(((g * KCH + k) * 32) + kk) * 32 + h]);
    }
    for (int i = gtid; i < 2 * 8 * 64 * 8; i += gsz) {
        int j = i & 7, lane = (i >> 3) & 63, nt = (i >> 9) & 7, c = i >> 12;
        int col = lane & 15, quad = lane >> 4;
        int kk = c * 32 + quad * 8 + j;
        int kcheb = kk >> 3, ch = kk & 7;
        int o = nt * 16 + col, g = o >> 5, h = o & 31;
        float v = (kcheb < KCH) ? Wx[(((g * KCH + kcheb) * 8) + ch) * 32 + h] : 0.f;
        Bxpack[i] = __float2half(v);
    }
}

// ---------------- Laplacian: pull CSR, fp16 features, ES-way edge split -----
template <int C, int ES>
__global__ void __launch_bounds__(256) k_lap_h(__half* __restrict__ outp,
                                               const __half* __restrict__ xin,
                                               const __half* __restrict__ xprev,
                                               float alpha, float beta,
                                               const int* __restrict__ rowptr,
                                               const unsigned int* __restrict__ cv,
                                               int N) {
    constexpr int Q = C / 8;
    constexpr int W = Q * ES;
    int idx = blockIdx.x * 256 + threadIdx.x;
    int node = idx / W;
    int r = idx % W;
    int q = r % Q, s = r / Q;
    if (node >= N) return;
    int beg = rowptr[node], end = rowptr[node + 1];
    float a0 = 0.f, a1 = 0.f, a2 = 0.f, a3 = 0.f, a4 = 0.f, a5 = 0.f, a6 = 0.f, a7 = 0.f;
    #pragma unroll 8
    for (int j = beg + s; j < end; j += ES) {
        unsigned int pv = cv[j];
        int pcol = (int)(pv & 0xffffu);
        float nv = __half2float(__ushort_as_half((unsigned short)(pv >> 16)));
        float4 raw = *(const float4*)(xin + (size_t)pcol * C + q * 8);
        const __half2* h = (const __half2*)&raw;
        float2 f0 = __half22float2(h[0]);
        float2 f1 = __half22float2(h[1]);
        float2 f2 = __half22float2(h[2]);
        float2 f3 = __half22float2(h[3]);
        a0 += nv * f0.x; a1 += nv * f0.y; a2 += nv * f1.x; a3 += nv * f1.y;
        a4 += nv * f2.x; a5 += nv * f2.y; a6 += nv * f3.x; a7 += nv * f3.y;
    }
    #pragma unroll
    for (int m = Q; m < W; m <<= 1) {
        a0 += __shfl_xor(a0, m, 64); a1 += __shfl_xor(a1, m, 64);
        a2 += __shfl_xor(a2, m, 64); a3 += __shfl_xor(a3, m, 64);
        a4 += __shfl_xor(a4, m, 64); a5 += __shfl_xor(a5, m, 64);
        a6 += __shfl_xor(a6, m, 64); a7 += __shfl_xor(a7, m, 64);
    }
    if (s != 0) return;
    size_t off = (size_t)node * C + q * 8;
    float r0 = alpha * a0, r1 = alpha * a1, r2 = alpha * a2, r3 = alpha * a3;
    float r4 = alpha * a4, r5 = alpha * a5, r6 = alpha * a6, r7 = alpha * a7;
    if (beta != 0.f) {
        float4 raw = *(const float4*)(xprev + off);
        const __half2* h = (const __half2*)&raw;
        float2 f0 = __half22float2(h[0]);
        float2 f1 = __half22float2(h[1]);
        float2 f2 = __half22float2(h[2]);
        float2 f3 = __half22float2(h[3]);
        r0 += beta * f0.x; r1 += beta * f0.y; r2 += beta * f1.x; r3 += beta * f1.y;
        r4 += beta * f2.x; r5 += beta * f2.y; r6 += beta * f3.x; r7 += beta * f3.y;
    }
    __half2 o[4];
    o[0] = __float22half2_rn(make_float2(r0, r1));
    o[1] = __float22half2_rn(make_float2(r2, r3));
    o[2] = __float22half2_rn(make_float2(r4, r5));
    o[3] = __float22half2_rn(make_float2(r6, r7));
    *(float4*)(outp + off) = *(float4*)o;
}

// ---------------- fused lap#4 + MFMA gate GEMM + LSTM (+ out head) ----------
// 16 nodes/block, 256 threads (4 waves). Phase 1: T4 = 2*L(T3)-T2 via the same
// high-TLP 16-lanes/node gather as standalone lap (grid = 1875 blocks keeps
// gather TLP). T4 goes to 1KB LDS only. Phase 2: GEMM M=16,N=128,K=64+160;
// wave w does nt={w,4+w}. Phase 3: stage C. Phase 4: LSTM. Phase 5: out head.
__global__ void __launch_bounds__(256) k_lapstep(
    const __half* __restrict__ xb, const __half* __restrict__ TXB,
    __half* __restrict__ THall, float* __restrict__ Cst,
    const __half* __restrict__ Bpack, const __half* __restrict__ Bxpack,
    const float* __restrict__ w_c, const float* __restrict__ bg,
    const float* __restrict__ W_lin, const float* __restrict__ b_lin,
    const int* __restrict__ perm, float* __restrict__ out,
    const int* __restrict__ rowptr, const unsigned int* __restrict__ cv,
    int t, int doOut, int N) {
    __shared__ __half T4s[16 * 32];
    __shared__ float Gs[16 * 128];
    __shared__ float Hs[16 * 33];
    int tid = threadIdx.x;
    int base = blockIdx.x * 16;
    int lane = tid & 63, wv = tid >> 6;
    int col = lane & 15, quad = lane >> 4;

    // phase 1: T4 = 2*L(T3) - T2 for block's 16 nodes (16 lanes/node)
    {
        const __half* T3 = THall + (size_t)3 * N * HID;
        const __half* T2 = THall + (size_t)2 * N * HID;
        int nl = tid >> 4;
        int r = tid & 15;
        int q = r & 3, s = r >> 2;
        int node = base + nl; if (node >= N) node = N - 1;
        int beg = rowptr[node], end = rowptr[node + 1];
        float a0 = 0.f, a1 = 0.f, a2 = 0.f, a3 = 0.f, a4 = 0.f, a5 = 0.f, a6 = 0.f, a7 = 0.f;
        #pragma unroll 8
        for (int j = beg + s; j < end; j += 4) {
            unsigned int pv = cv[j];
            int pcol = (int)(pv & 0xffffu);
            float nv = __half2float(__ushort_as_half((unsigned short)(pv >> 16)));
            float4 raw = *(const float4*)(T3 + (size_t)pcol * HID + q * 8);
            const __half2* h = (const __half2*)&raw;
            float2 f0 = __half22float2(h[0]);
            float2 f1 = __half22float2(h[1]);
            float2 f2 = __half22float2(h[2]);
            float2 f3 = __half22float2(h[3]);
            a0 += nv * f0.x; a1 += nv * f0.y; a2 += nv * f1.x; a3 += nv * f1.y;
            a4 += nv * f2.x; a5 += nv * f2.y; a6 += nv * f3.x; a7 += nv * f3.y;
        }
        #pragma unroll
        for (int m = 4; m < 16; m <<= 1) {
            a0 += __shfl_xor(a0, m, 64); a1 += __shfl_xor(a1, m, 64);
            a2 += __shfl_xor(a2, m, 64); a3 += __shfl_xor(a3, m, 64);
            a4 += __shfl_xor(a4, m, 64); a5 += __shfl_xor(a5, m, 64);
            a6 += __shfl_xor(a6, m, 64); a7 += __shfl_xor(a7, m, 64);
        }
        if (s == 0) {
            float4 raw = *(const float4*)(T2 + (size_t)node * HID + q * 8);
            const __half2* h = (const __half2*)&raw;
            float2 f0 = __half22float2(h[0]);
            float2 f1 = __half22float2(h[1]);
            float2 f2 = __half22float2(h[2]);
            float2 f3 = __half22float2(h[3]);
            __half2 o[4];
            o[0] = __float22half2_rn(make_float2(2.f * a0 - f0.x, 2.f * a1 - f0.y));
            o[1] = __float22half2_rn(make_float2(2.f * a2 - f1.x, 2.f * a3 - f1.y));
            o[2] = __float22half2_rn(make_float2(2.f * a4 - f2.x, 2.f * a5 - f2.y));
            o[3] = __float22half2_rn(make_float2(2.f * a6 - f3.x, 2.f * a7 - f3.y));
            *(float4*)(T4s + nl * 32 + q * 8) = *(float4*)o;
        }
    }
    __syncthreads();

    // phase 2: gate GEMM (wave wv: nt = {wv, 4+wv})
    int node_a = base + col; if (node_a >= N) node_a = N - 1;
    f32x4_t acc[2];
    #pragma unroll
    for (int i = 0; i < 2; ++i) {
        float b = bg[(wv + 4 * i) * 16 + col];
        acc[i][0] = b; acc[i][1] = b; acc[i][2] = b; acc[i][3] = b;
    }
    const half8_t* Bx = (const half8_t*)Bxpack;
    const half8_t* Bp = (const half8_t*)Bpack;
    {
        const __half* sp0 = (quad == 0)
            ? (xb + (size_t)node_a * 64 + t * 8)
            : (TXB + ((size_t)(quad - 1) * N + node_a) * 64 + t * 8);
        half8_t ax0 = *(const half8_t*)sp0;
        half8_t ax1 = {};
        if (quad == 0)
            ax1 = *(const half8_t*)(TXB + ((size_t)3 * N + node_a) * 64 + t * 8);
        #pragma unroll
        for (int i = 0; i < 2; ++i) {
            int nt = wv + 4 * i;
            acc[i] = __builtin_amdgcn_mfma_f32_16x16x32_f16(ax0, Bx[nt * 64 + lane], acc[i], 0, 0, 0);
            acc[i] = __builtin_amdgcn_mfma_f32_16x16x32_f16(ax1, Bx[(8 + nt) * 64 + lane], acc[i], 0, 0, 0);
        }
    }
    #pragma unroll
    for (int k = 0; k < 4; ++k) {
        half8_t a = *(const half8_t*)(THall + ((size_t)k * N + node_a) * 32 + quad * 8);
        #pragma unroll
        for (int i = 0; i < 2; ++i) {
            int nt = wv + 4 * i;
            acc[i] = __builtin_amdgcn_mfma_f32_16x16x32_f16(a, Bp[(k * 8 + nt) * 64 + lane], acc[i], 0, 0, 0);
        }
    }
    {
        half8_t a = *(const half8_t*)(T4s + col * 32 + quad * 8);
        #pragma unroll
        for (int i = 0; i < 2; ++i) {
            int nt = wv + 4 * i;
            acc[i] = __builtin_amdgcn_mfma_f32_16x16x32_f16(a, Bp[(4 * 8 + nt) * 64 + lane], acc[i], 0, 0, 0);
        }
    }

    // phase 3: stage gate pre-acts
    #pragma unroll
    for (int i = 0; i < 2; ++i) {
        int nt = wv + 4 * i;
        #pragma unroll
        for (int reg = 0; reg < 4; ++reg)
            Gs[(quad * 4 + reg) * 128 + nt * 16 + col] = acc[i][reg];
    }
    __syncthreads();

    // phase 4: LSTM pointwise
    #pragma unroll
    for (int pp = 0; pp < 2; ++pp) {
        int p = tid + pp * 256;
        int nl = p >> 5, h = p & 31;
        int node = base + nl;
        if (node < N) {
            const float* g = Gs + nl * 128;
            size_t idx = (size_t)node * 32 + h;
            float Co = Cst[idx];
            float I  = sigmoidf_(g[h]      + w_c[h]      * Co);
            float F  = sigmoidf_(g[32 + h] + w_c[32 + h] * Co);
            float Tg = tanhf_(g[64 + h]);
            float Cn = F * Co + I * Tg;
            float O  = sigmoidf_(g[96 + h] + w_c[64 + h] * Cn);
            float Hn = O * tanhf_(Cn);
            Cst[idx] = Cn;
            THall[idx] = __float2half(Hn);
            if (doOut) Hs[nl * 33 + h] = fmaxf(Hn, 0.f);
        } else if (doOut) {
            Hs[nl * 33 + h] = 0.f;
        }
    }

    // phase 5: output head
    if (doOut) {
        __syncthreads();
        if (tid < 128) {
            int nl = tid >> 3, pp = tid & 7;
            int node = base + nl;
            if (node < N) {
                float a0 = b_lin[pp];
                const float* hp = Hs + nl * 33;
                #pragma unroll
                for (int h = 0; h < HID; ++h)
                    a0 += hp[h] * W_lin[pp * HID + h];
                out[(size_t)perm[node] * PERIODS + pp] = a0;
            }
        }
    }
}

// ---------------- fused lapx#4 + t=0 x-GEMM + pointwise ----------------------
// 16 nodes/block. Phase 1: TXB3 = 2*L(TXB2) - TXB1 (C=64, 16 lanes/node),
// written globally (needed by later timesteps) AND kept in LDS for the t=0
// GEMM. Phase 2-4: x-GEMM + LSTM pointwise with C=H=0.
__global__ void __launch_bounds__(256) k_lapstep0(
    const __half* __restrict__ xb, const __half* __restrict__ TXB,
    __half* __restrict__ TXB3, __half* __restrict__ THall, float* __restrict__ Cst,
    const __half* __restrict__ Bxpack,
    const float* __restrict__ w_c, const float* __restrict__ bg,
    const int* __restrict__ rowptr, const unsigned int* __restrict__ cv, int N) {
    __shared__ __half X3s[16 * 64];
    __shared__ float Gs[16 * 128];
    int tid = threadIdx.x;
    int base = blockIdx.x * 16;
    int lane = tid & 63, wv = tid >> 6;
    int col = lane & 15, quad = lane >> 4;

    // phase 1: TXB3 rows for block's 16 nodes (C=64: Q=8, s in {0,1})
    {
        const __half* T2 = TXB + (size_t)2 * N * 64;
        const __half* T1 = TXB + (size_t)1 * N * 64;
        int nl = tid >> 4;
        int r = tid & 15;
        int q = r & 7, s = r >> 3;
        int node = base + nl; if (node >= N) node = N - 1;
        int beg = rowptr[node], end = rowptr[node + 1];
        float a0 = 0.f, a1 = 0.f, a2 = 0.f, a3 = 0.f, a4 = 0.f, a5 = 0.f, a6 = 0.f, a7 = 0.f;
        #pragma unroll 8
        for (int j = beg + s; j < end; j += 2) {
            unsigned int pv = cv[j];
            int pcol = (int)(pv & 0xffffu);
            float nv = __half2float(__ushort_as_half((unsigned short)(pv >> 16)));
            float4 raw = *(const float4*)(T2 + (size_t)pcol * 64 + q * 8);
            const __half2* h = (const __half2*)&raw;
            float2 f0 = __half22float2(h[0]);
            float2 f1 = __half22float2(h[1]);
            float2 f2 = __half22float2(h[2]);
            float2 f3 = __half22float2(h[3]);
            a0 += nv * f0.x; a1 += nv * f0.y; a2 += nv * f1.x; a3 += nv * f1.y;
            a4 += nv * f2.x; a5 += nv * f2.y; a6 += nv * f3.x; a7 += nv * f3.y;
        }
        a0 += __shfl_xor(a0, 8, 64); a1 += __shfl_xor(a1, 8, 64);
        a2 += __shfl_xor(a2, 8, 64); a3 += __shfl_xor(a3, 8, 64);
        a4 += __shfl_xor(a4, 8, 64); a5 += __shfl_xor(a5, 8, 64);
        a6 += __shfl_xor(a6, 8, 64); a7 += __shfl_xor(a7, 8, 64);
        if (s == 0) {
            size_t off = (size_t)node * 64 + q * 8;
            float4 raw = *(const float4*)(T1 + off);
            const __half2* h = (const __half2*)&raw;
            float2 f0 = __half22float2(h[0]);
            float2 f1 = __half22float2(h[1]);
            float2 f2 = __half22float2(h[2]);
            float2 f3 = __half22float2(h[3]);
            __half2 o[4];
            o[0] = __float22half2_rn(make_float2(2.f * a0 - f0.x, 2.f * a1 - f0.y));
            o[1] = __float22half2_rn(make_float2(2.f * a2 - f1.x, 2.f * a3 - f1.y));
            o[2] = __float22half2_rn(make_float2(2.f * a4 - f2.x, 2.f * a5 - f2.y));
            o[3] = __float22half2_rn(make_float2(2.f * a6 - f3.x, 2.f * a7 - f3.y));
            *(float4*)(TXB3 + off) = *(float4*)o;
            *(float4*)(X3s + nl * 64 + q * 8) = *(float4*)o;
        }
    }
    __syncthreads();

    // phase 2: x-GEMM (t = 0)
    int node_a = base + col; if (node_a >= N) node_a = N - 1;
    f32x4_t acc[2];
    #pragma unroll
    for (int i = 0; i < 2; ++i) {
        float b = bg[(wv + 4 * i) * 16 + col];
        acc[i][0] = b; acc[i][1] = b; acc[i][2] = b; acc[i][3] = b;
    }
    const half8_t* Bx = (const half8_t*)Bxpack;
    {
        const __half* sp0 = (quad == 0)
            ? (xb + (size_t)node_a * 64)
            : (TXB + ((size_t)(quad - 1) * N + node_a) * 64);
        half8_t ax0 = *(const half8_t*)sp0;
        half8_t ax1 = {};
        if (quad == 0)
            ax1 = *(const half8_t*)(X3s + col * 64);   // t = 0 slice
        #pragma unroll
        for (int i = 0; i < 2; ++i) {
            int nt = wv + 4 * i;
            acc[i] = __builtin_amdgcn_mfma_f32_16x16x32_f16(ax0, Bx[nt * 64 + lane], acc[i], 0, 0, 0);
            acc[i] = __builtin_amdgcn_mfma_f32_16x16x32_f16(ax1, Bx[(8 + nt) * 64 + lane], acc[i], 0, 0, 0);
        }
    }

    // phase 3: stage
    #pragma unroll
    for (int i = 0; i < 2; ++i) {
        int nt = wv + 4 * i;
        #pragma unroll
        for (int reg = 0; reg < 4; ++reg)
            Gs[(quad * 4 + reg) * 128 + nt * 16 + col] = acc[i][reg];
    }
    __syncthreads();

    // phase 4: LSTM pointwise with C = 0
    #pragma unroll
    for (int pp = 0; pp < 2; ++pp) {
        int p = tid + pp * 256;
        int nl = p >> 5, h = p & 31;
        int node = base + nl;
        if (node < N) {
            const float* g = Gs + nl * 128;
            size_t idx = (size_t)node * 32 + h;
            float I  = sigmoidf_(g[h]);
            float Tg = tanhf_(g[64 + h]);
            float Cn = I * Tg;
            float O  = sigmoidf_(g[96 + h] + w_c[64 + h] * Cn);
            Cst[idx] = Cn;
            THall[idx] = __float2half(O * tanhf_(Cn));
        }
    }
}

// ---------------- launch ----------------

extern "C" void kernel_launch(void* const* d_in, const int* in_sizes, int n_in,
                              void* d_out, int out_size, void* d_ws, size_t ws_size,
                              hipStream_t stream) {
    const float* xall  = (const float*)d_in[0];
    const int*   ei    = (const int*)d_in[1];
    const float* Wx    = (const float*)d_in[2];
    const float* Wh    = (const float*)d_in[3];
    const float* w_c   = (const float*)d_in[4];
    const float* bg    = (const float*)d_in[5];
    const float* W_lin = (const float*)d_in[6];
    const float* b_lin = (const float*)d_in[7];
    float* out = (float*)d_out;

    const int E = in_sizes[1] / 2;
    const int N = in_sizes[0] / (T_STEPS * F_IN);
    const int NT = (N + 255) / 256;
    const int* src = ei;
    const int* dst = ei + E;

    char* p = (char*)d_ws;
    auto carve = [&](size_t bytes) -> void* {
        void* r = (void*)p;
        p += (bytes + 255) & ~(size_t)255;
        return r;
    };
    // zero block: degi, cnt, fill, Cst
    char* zero_begin = p;
    int*    degi  = (int*)   carve((size_t)N * 4);
    int*    cnt   = (int*)   carve((size_t)N * 4);
    int*    fill  = (int*)   carve((size_t)N * 4);
    float*  Cst   = (float*) carve((size_t)N * HID * 4);
    size_t zero_bytes = (size_t)(p - zero_begin);
    __half* THall = (__half*)carve((size_t)4 * N * HID * 2);   // slices 0..3
    int*    hist     = (int*)   carve((size_t)256 * NT * 4);
    int*    histbase = (int*)   carve(((size_t)256 * NT + 1) * 4);
    float*  dis      = (float*) carve((size_t)N * 4);
    int*    perm     = (int*)   carve((size_t)N * 4);
    int*    iperm    = (int*)   carve((size_t)N * 4);
    int*    cntp     = (int*)   carve((size_t)N * 4);
    int*    rowptr   = (int*)   carve((size_t)(N + 1) * 4);
    unsigned int* cv = (unsigned int*)carve((size_t)E * 4);
    __half* xb       = (__half*)carve((size_t)N * 64 * 2);
    __half* TXB      = (__half*)carve((size_t)4 * N * 64 * 2);
    __half* Bpack    = (__half*)carve((size_t)KCH * 8 * 64 * 8 * 2);
    __half* Bxpack   = (__half*)carve((size_t)2 * 8 * 64 * 8 * 2);

    hipMemsetAsync(zero_begin, 0, zero_bytes, stream);

    const int TB = 256;
    const int gE = (E + TB - 1) / TB;
    k_count<<<gE, TB, 0, stream>>>(src, dst, degi, cnt, E);
    k_hist2<<<NT, TB, 0, stream>>>(cnt, hist, N, NT);
    k_scan<<<1, 1024, 0, stream>>>(hist, histbase, 256 * NT);
    k_permscat2<<<NT, TB, 0, stream>>>(cnt, degi, histbase, perm, iperm, cntp, dis, N, NT);
    k_scan<<<1, 1024, 0, stream>>>(cntp, rowptr, N);
    k_scatxt<<<gE, TB, 0, stream>>>(src, dst, dis, rowptr, iperm, fill, cv, xall, xb,
                                    Wh, Bpack, Wx, Bxpack, N, E);

    // x-phase Chebyshev: 3 standalone laps + fused (lapx#4 + t=0 step)
    __half* TXB0 = TXB;
    __half* TXB1 = TXB + (size_t)N * 64;
    __half* TXB2 = TXB + (size_t)2 * N * 64;
    __half* TXB3 = TXB + (size_t)3 * N * 64;
    const int lapx_grid = (N * 32 + TB - 1) / TB;
    k_lap_h<64, 4><<<lapx_grid, TB, 0, stream>>>(TXB0, xb,   nullptr, 1.f,  0.f, rowptr, cv, N);
    k_lap_h<64, 4><<<lapx_grid, TB, 0, stream>>>(TXB1, TXB0, xb,      2.f, -1.f, rowptr, cv, N);
    k_lap_h<64, 4><<<lapx_grid, TB, 0, stream>>>(TXB2, TXB1, TXB0,    2.f, -1.f, rowptr, cv, N);

    const int lapstep_grid = (N + 15) / 16;
    const int laph_grid = (N * 16 + TB - 1) / TB;
    __half* TH0 = THall;
    __half* TH1 = THall + (size_t)N * HID;
    __half* TH2 = THall + (size_t)2 * N * HID;
    __half* TH3 = THall + (size_t)3 * N * HID;

    // t = 0: fused lapx#4 + x-GEMM + pointwise (H0 = C0 = 0)
    k_lapstep0<<<lapstep_grid, TB, 0, stream>>>(xb, TXB, TXB3, THall, Cst, Bxpack,
                                                w_c, bg, rowptr, cv, N);

    for (int t = 1; t < T_STEPS; ++t) {
        k_lap_h<HID, 4><<<laph_grid, TB, 0, stream>>>(TH1, TH0, nullptr, 1.f,  0.f, rowptr, cv, N);
        k_lap_h<HID, 4><<<laph_grid, TB, 0, stream>>>(TH2, TH1, TH0,     2.f, -1.f, rowptr, cv, N);
        k_lap_h<HID, 4><<<laph_grid, TB, 0, stream>>>(TH3, TH2, TH1,     2.f, -1.f, rowptr, cv, N);
        k_lapstep<<<lapstep_grid, TB, 0, stream>>>(xb, TXB, THall, Cst, Bpack, Bxpack,
                                                   w_c, bg, W_lin, b_lin, perm, out,
                                                   rowptr, cv, t,
                                                   (t == T_STEPS - 1) ? 1 : 0, N);
    }
}